// Round 9
// baseline (26.554 us; speedup 1.0000x reference)
//
#include <hip/hip_runtime.h>
#include <hip/hip_bf16.h>

// Fully fused, band=4. Grid 448 blocks (64 opair x 7 band) x 256 threads.
// LDS layout k-INTERLEAVED: sB[l][pr][px][k], l=0..31, pr=0..5, px=0..29,
// k=0..1. Row stride 60 floats, l stride 372 floats (60*6 + 12 pad;
// 372 mod 32 = 20 -> 8 distinct bank groups for the l8 lane classes).
// Total 47,616 B -> 3 blocks/CU -> 12 waves/CU.
//
// Phase A: 192 tasks (l, pr); loads x rows 2l,2l+1 once, computes both
//   k-channels, writes px-pair-interleaved float4s {p_k0, p_k1, p+1_k0, p+1_k1}.
// Phase B: thread = (oo, rp, st, l8). 2x4 output tile. Per (li,q): 3 b128
//   reads give 6 k-paired taps; float2 elementwise FMA with k-paired wreg
//   (v_pk_fma_f32-eligible). k-fold then 3-step shfl_xor over l8; lane
//   l8==0 stores two float4.
__global__ __launch_bounds__(256, 3) void fused_kernel(
    const float* __restrict__ x,    // [64][28][28]
    const float* __restrict__ w1,   // [128][32][3][3][2]
    const float* __restrict__ w2,   // [64][3][2]
    float* __restrict__ y)          // [128][28][28]
{
    __shared__ __align__(16) float sB[32 * 372];   // 47,616 B

    const int b     = blockIdx.x;     // 0..447
    const int opair = b / 7;
    const int band  = b % 7;
    const int tid   = threadIdx.x;

    // ---------------- Phase B thread mapping (needed for prefetch) --------
    const int l8      = tid & 7;          // lane bits 0-2: l-split
    const int strip   = tid >> 3;         // 0..31, active < 28
    const bool act    = (strip < 28);
    const int sclp    = act ? strip : 0;
    const int oo      = sclp / 14;
    const int rem     = sclp % 14;
    const int rp      = rem / 7;          // output row-pair within band
    const int st      = rem % 7;          // 4-col strip
    const int o       = opair * 2 + oo;

    // ---------------- Weight prefetch (before phase A) ----------------
    // wreg[li][t] = w1[o][l8+8li][t/3][t%3][0..1] as float2 {k0,k1}
    float2 wreg[4][9];
    {
        const float* wb = w1 + o * 576 + l8 * 18;   // w1[o][l][dy][s][k]
        #pragma unroll
        for (int li = 0; li < 4; ++li)
            #pragma unroll
            for (int t = 0; t < 9; ++t)
                wreg[li][t] = *(const float2*)(wb + li * 144 + t * 2);
    }

    // ---------------- Phase A: stage1+2 into LDS (l-paired, k-interleaved) -
    if (tid < 192) {
        const int l  = tid / 6;            // 0..31
        const int pr = tid % 6;            // padded row 0..5
        const int m  = band * 4 + pr - 1;  // input row
        const int j0 = 2 * l;
        float* dst = &sB[l * 372 + pr * 60];
        if (m < 0 || m > 27) {
            #pragma unroll
            for (int t = 0; t < 15; ++t)
                ((float4*)dst)[t] = make_float4(0.f, 0.f, 0.f, 0.f);
        } else {
            const float* xr0 = x + (j0 * 28 + m) * 28;
            const float* xr1 = xr0 + 28 * 28;
            // w2[j][i][k]: float2 at (j,i) = {k0, k1}
            const float2 a0 = *(const float2*)(w2 + j0 * 6 + 0);
            const float2 a1 = *(const float2*)(w2 + j0 * 6 + 2);
            const float2 a2 = *(const float2*)(w2 + j0 * 6 + 4);
            const float2 b0 = *(const float2*)(w2 + j0 * 6 + 6);
            const float2 b1 = *(const float2*)(w2 + j0 * 6 + 8);
            const float2 b2 = *(const float2*)(w2 + j0 * 6 + 10);

            float4 pv0 = make_float4(0.f, 0.f, 0.f, 0.f);
            float4 pv1 = make_float4(0.f, 0.f, 0.f, 0.f);
            #pragma unroll
            for (int t = 0; t < 7; ++t) {
                float4 v0 = ((const float4*)xr0)[t];
                float4 v1 = ((const float4*)xr1)[t];
                // k0/k1 outputs for px 4t..4t+3
                float o0x = a0.x*pv0.z + a1.x*pv0.w + a2.x*v0.x
                          + b0.x*pv1.z + b1.x*pv1.w + b2.x*v1.x;
                float o1x = a0.y*pv0.z + a1.y*pv0.w + a2.y*v0.x
                          + b0.y*pv1.z + b1.y*pv1.w + b2.y*v1.x;
                float o0y = a0.x*pv0.w + a1.x*v0.x + a2.x*v0.y
                          + b0.x*pv1.w + b1.x*v1.x + b2.x*v1.y;
                float o1y = a0.y*pv0.w + a1.y*v0.x + a2.y*v0.y
                          + b0.y*pv1.w + b1.y*v1.x + b2.y*v1.y;
                float o0z = a0.x*v0.x + a1.x*v0.y + a2.x*v0.z
                          + b0.x*v1.x + b1.x*v1.y + b2.x*v1.z;
                float o1z = a0.y*v0.x + a1.y*v0.y + a2.y*v0.z
                          + b0.y*v1.x + b1.y*v1.y + b2.y*v1.z;
                float o0w = a0.x*v0.y + a1.x*v0.z + a2.x*v0.w
                          + b0.x*v1.y + b1.x*v1.z + b2.x*v1.w;
                float o1w = a0.y*v0.y + a1.y*v0.z + a2.y*v0.w
                          + b0.y*v1.y + b1.y*v1.z + b2.y*v1.w;
                if (t == 0) { o0x = 0.f; o1x = 0.f; }   // px 0 left zero-pad
                ((float4*)dst)[2*t]     = make_float4(o0x, o1x, o0y, o1y);
                ((float4*)dst)[2*t + 1] = make_float4(o0z, o1z, o0w, o1w);
                pv0 = v0; pv1 = v1;
            }
            // px 28 (taps xr[26], xr[27]); px 29 right pad
            float t28_0 = a0.x*pv0.z + a1.x*pv0.w + b0.x*pv1.z + b1.x*pv1.w;
            float t28_1 = a0.y*pv0.z + a1.y*pv0.w + b0.y*pv1.z + b1.y*pv1.w;
            ((float4*)dst)[14] = make_float4(t28_0, t28_1, 0.f, 0.f);
        }
    }
    __syncthreads();

    // ---------------- Phase B: 3x3x64 conv, 2x4 tile, k-paired ------------
    float2 A00 = {0,0}, A01 = {0,0}, A02 = {0,0}, A03 = {0,0};
    float2 A10 = {0,0}, A11 = {0,0}, A12 = {0,0}, A13 = {0,0};

    #pragma unroll
    for (int li = 0; li < 4; ++li) {
        const int l = l8 + li * 8;
        const float* sa = &sB[l * 372 + (rp * 2) * 60 + st * 8];
        #pragma unroll
        for (int q = 0; q < 4; ++q) {
            const float* row = sa + q * 60;
            float4 T0 = *(const float4*)(row);
            float4 T1 = *(const float4*)(row + 4);
            float4 T2 = *(const float4*)(row + 8);
            float2 p0 = make_float2(T0.x, T0.y);
            float2 p1 = make_float2(T0.z, T0.w);
            float2 p2 = make_float2(T1.x, T1.y);
            float2 p3 = make_float2(T1.z, T1.w);
            float2 p4 = make_float2(T2.x, T2.y);
            float2 p5 = make_float2(T2.z, T2.w);
            if (q < 3) {            // output row 0, tap dy=q
                float2 W0 = wreg[li][q * 3 + 0];
                float2 W1 = wreg[li][q * 3 + 1];
                float2 W2 = wreg[li][q * 3 + 2];
                A00.x += W0.x*p0.x + W1.x*p1.x + W2.x*p2.x;
                A00.y += W0.y*p0.y + W1.y*p1.y + W2.y*p2.y;
                A01.x += W0.x*p1.x + W1.x*p2.x + W2.x*p3.x;
                A01.y += W0.y*p1.y + W1.y*p2.y + W2.y*p3.y;
                A02.x += W0.x*p2.x + W1.x*p3.x + W2.x*p4.x;
                A02.y += W0.y*p2.y + W1.y*p3.y + W2.y*p4.y;
                A03.x += W0.x*p3.x + W1.x*p4.x + W2.x*p5.x;
                A03.y += W0.y*p3.y + W1.y*p4.y + W2.y*p5.y;
            }
            if (q >= 1) {           // output row 1, tap dy=q-1
                float2 W0 = wreg[li][(q - 1) * 3 + 0];
                float2 W1 = wreg[li][(q - 1) * 3 + 1];
                float2 W2 = wreg[li][(q - 1) * 3 + 2];
                A10.x += W0.x*p0.x + W1.x*p1.x + W2.x*p2.x;
                A10.y += W0.y*p0.y + W1.y*p1.y + W2.y*p2.y;
                A11.x += W0.x*p1.x + W1.x*p2.x + W2.x*p3.x;
                A11.y += W0.y*p1.y + W1.y*p2.y + W2.y*p3.y;
                A12.x += W0.x*p2.x + W1.x*p3.x + W2.x*p4.x;
                A12.y += W0.y*p2.y + W1.y*p3.y + W2.y*p4.y;
                A13.x += W0.x*p3.x + W1.x*p4.x + W2.x*p5.x;
                A13.y += W0.y*p3.y + W1.y*p4.y + W2.y*p5.y;
            }
        }
    }

    // k-fold, then butterfly reduce over l8 (lane bits 0-2)
    float acc00 = A00.x + A00.y, acc01 = A01.x + A01.y;
    float acc02 = A02.x + A02.y, acc03 = A03.x + A03.y;
    float acc10 = A10.x + A10.y, acc11 = A11.x + A11.y;
    float acc12 = A12.x + A12.y, acc13 = A13.x + A13.y;

    #pragma unroll
    for (int m = 1; m <= 4; m <<= 1) {
        acc00 += __shfl_xor(acc00, m); acc01 += __shfl_xor(acc01, m);
        acc02 += __shfl_xor(acc02, m); acc03 += __shfl_xor(acc03, m);
        acc10 += __shfl_xor(acc10, m); acc11 += __shfl_xor(acc11, m);
        acc12 += __shfl_xor(acc12, m); acc13 += __shfl_xor(acc13, m);
    }

    if (act && l8 == 0) {
        const int R0 = band * 4 + rp * 2;
        float* yp = y + (o * 28 + R0) * 28 + st * 4;
        *(float4*)yp        = make_float4(acc00, acc01, acc02, acc03);
        *(float4*)(yp + 28) = make_float4(acc10, acc11, acc12, acc13);
    }
}

extern "C" void kernel_launch(void* const* d_in, const int* in_sizes, int n_in,
                              void* d_out, int out_size, void* d_ws, size_t ws_size,
                              hipStream_t stream) {
    const float* x  = (const float*)d_in[0];   // (1,64,28,28) fp32
    const float* w1 = (const float*)d_in[1];   // (128,32,3,3,2) fp32
    const float* w2 = (const float*)d_in[2];   // (64,3,2) fp32
    float* yout = (float*)d_out;               // (1,128,28,28) fp32

    fused_kernel<<<dim3(448), dim3(256), 0, stream>>>(x, w1, w2, yout);
}

// Round 10
// 14.104 us; speedup vs baseline: 1.8828x; 1.8828x over previous
//
#include <hip/hip_runtime.h>
#include <hip/hip_bf16.h>

// Fully fused, band=4. Grid 448 blocks (64 opair x 7 band) x 256 threads.
// LDS 56,320B -> 2 blocks/CU -> 8 waves/CU. launch_bounds(256,2): DO NOT
// raise to 3 — VGPR cap 84 forces scratch spills (R9: 13.9 -> 26.6 us,
// FETCH_SIZE 21.7MB of spill traffic).
//
// Phase A (l-paired, single round): 192 tasks = (l 0..31, pr 0..5). Each task
//   loads x rows 2l and 2l+1 ONCE (14 float4) and produces BOTH stage-1
//   channels c=2l (k=0) and c=2l+1 (k=1) via the float2 k-pair weights.
// Phase B: thread = (oo, rp, st, l8). 2x4 output tile, 8-way l-split on lane
//   bits 0-2, weights prefetched to registers before phase A, 3-step
//   shfl_xor reduce, lane l8==0 stores two float4.
__global__ __launch_bounds__(256, 2) void fused_kernel(
    const float* __restrict__ x,    // [64][28][28]
    const float* __restrict__ w1,   // [128][32][3][3][2]
    const float* __restrict__ w2,   // [64][3][2]
    float* __restrict__ y)          // [128][28][28]
{
    __shared__ __align__(16) float sA[64 * 220];   // 56,320 B

    const int b     = blockIdx.x;     // 0..447
    const int opair = b / 7;
    const int band  = b % 7;
    const int tid   = threadIdx.x;

    // ---------------- Phase B thread mapping (needed for prefetch) --------
    const int l8      = tid & 7;          // lane bits 0-2: l-split
    const int strip   = tid >> 3;         // 0..31, active < 28
    const bool act    = (strip < 28);
    const int sclp    = act ? strip : 0;
    const int oo      = sclp / 14;
    const int rem     = sclp % 14;
    const int rp      = rem / 7;          // output row-pair within band
    const int st      = rem % 7;          // 4-col strip
    const int o       = opair * 2 + oo;

    // ---------------- Weight prefetch (before phase A) ----------------
    float2 wreg[4][9];
    {
        const float* wb = w1 + o * 576 + l8 * 18;   // w1[o][l][dy][s][k]
        #pragma unroll
        for (int li = 0; li < 4; ++li)
            #pragma unroll
            for (int t = 0; t < 9; ++t)
                wreg[li][t] = *(const float2*)(wb + li * 144 + t * 2);
    }

    // ---------------- Phase A: stage1+2 into LDS (l-paired) ----------------
    if (tid < 192) {
        const int l  = tid / 6;            // 0..31
        const int pr = tid % 6;            // padded row 0..5
        const int m  = band * 4 + pr - 1;  // input row
        const int j0 = 2 * l;
        float* dst0 = &sA[(2 * l)     * 220 + pr * 36];  // k=0 channel
        float* dst1 = &sA[(2 * l + 1) * 220 + pr * 36];  // k=1 channel
        if (m < 0 || m > 27) {
            #pragma unroll
            for (int t = 0; t < 7; ++t) {
                ((float4*)dst0)[t] = make_float4(0.f, 0.f, 0.f, 0.f);
                ((float4*)dst1)[t] = make_float4(0.f, 0.f, 0.f, 0.f);
            }
            ((float2*)dst0)[14] = make_float2(0.f, 0.f);
            ((float2*)dst1)[14] = make_float2(0.f, 0.f);
        } else {
            const float* xr0 = x + (j0 * 28 + m) * 28;
            const float* xr1 = xr0 + 28 * 28;
            // w2[j][i][k]: float2 at (j,i) = (k0, k1) pair
            const float2 a0 = *(const float2*)(w2 + j0 * 6 + 0);
            const float2 a1 = *(const float2*)(w2 + j0 * 6 + 2);
            const float2 a2 = *(const float2*)(w2 + j0 * 6 + 4);
            const float2 b0 = *(const float2*)(w2 + j0 * 6 + 6);
            const float2 b1 = *(const float2*)(w2 + j0 * 6 + 8);
            const float2 b2 = *(const float2*)(w2 + j0 * 6 + 10);

            float4 pv0 = make_float4(0.f, 0.f, 0.f, 0.f);
            float4 pv1 = make_float4(0.f, 0.f, 0.f, 0.f);
            #pragma unroll
            for (int t = 0; t < 7; ++t) {
                float4 v0 = ((const float4*)xr0)[t];
                float4 v1 = ((const float4*)xr1)[t];
                float4 o0, o1;
                o0.x = a0.x * pv0.z + a1.x * pv0.w + a2.x * v0.x
                     + b0.x * pv1.z + b1.x * pv1.w + b2.x * v1.x;
                o0.y = a0.x * pv0.w + a1.x * v0.x + a2.x * v0.y
                     + b0.x * pv1.w + b1.x * v1.x + b2.x * v1.y;
                o0.z = a0.x * v0.x + a1.x * v0.y + a2.x * v0.z
                     + b0.x * v1.x + b1.x * v1.y + b2.x * v1.z;
                o0.w = a0.x * v0.y + a1.x * v0.z + a2.x * v0.w
                     + b0.x * v1.y + b1.x * v1.z + b2.x * v1.w;
                o1.x = a0.y * pv0.z + a1.y * pv0.w + a2.y * v0.x
                     + b0.y * pv1.z + b1.y * pv1.w + b2.y * v1.x;
                o1.y = a0.y * pv0.w + a1.y * v0.x + a2.y * v0.y
                     + b0.y * pv1.w + b1.y * v1.x + b2.y * v1.y;
                o1.z = a0.y * v0.x + a1.y * v0.y + a2.y * v0.z
                     + b0.y * v1.x + b1.y * v1.y + b2.y * v1.z;
                o1.w = a0.y * v0.y + a1.y * v0.z + a2.y * v0.w
                     + b0.y * v1.y + b1.y * v1.z + b2.y * v1.w;
                if (t == 0) { o0.x = 0.f; o1.x = 0.f; }  // px 0 left zero-pad
                ((float4*)dst0)[t] = o0;
                ((float4*)dst1)[t] = o1;
                pv0 = v0; pv1 = v1;
            }
            // px 28 (taps xr[26], xr[27]) and px 29 (right pad)
            float t28_0 = a0.x * pv0.z + a1.x * pv0.w
                        + b0.x * pv1.z + b1.x * pv1.w;
            float t28_1 = a0.y * pv0.z + a1.y * pv0.w
                        + b0.y * pv1.z + b1.y * pv1.w;
            ((float2*)dst0)[14] = make_float2(t28_0, 0.f);
            ((float2*)dst1)[14] = make_float2(t28_1, 0.f);
        }
    }
    __syncthreads();

    // ---------------- Phase B: 3x3x64 conv, 2x4 tile ----------------
    float acc00 = 0.f, acc01 = 0.f, acc02 = 0.f, acc03 = 0.f;
    float acc10 = 0.f, acc11 = 0.f, acc12 = 0.f, acc13 = 0.f;

    #pragma unroll
    for (int li = 0; li < 4; ++li) {
        #pragma unroll
        for (int ch = 0; ch < 2; ++ch) {
            const int c = (l8 + li * 8) * 2 + ch;
            const float* sa = &sA[c * 220 + (rp * 2) * 36 + st * 4];
            #pragma unroll
            for (int q = 0; q < 4; ++q) {
                float4 t0 = *(const float4*)(sa + q * 36);
                float2 t1 = *(const float2*)(sa + q * 36 + 4);
                if (q < 3) {            // output row 0, tap dy=q
                    float2 W0 = wreg[li][q * 3 + 0];
                    float2 W1 = wreg[li][q * 3 + 1];
                    float2 W2 = wreg[li][q * 3 + 2];
                    float wa  = ch ? W0.y : W0.x;
                    float wbv = ch ? W1.y : W1.x;
                    float wc  = ch ? W2.y : W2.x;
                    acc00 += wa * t0.x + wbv * t0.y + wc * t0.z;
                    acc01 += wa * t0.y + wbv * t0.z + wc * t0.w;
                    acc02 += wa * t0.z + wbv * t0.w + wc * t1.x;
                    acc03 += wa * t0.w + wbv * t1.x + wc * t1.y;
                }
                if (q >= 1) {           // output row 1, tap dy=q-1
                    float2 W0 = wreg[li][(q - 1) * 3 + 0];
                    float2 W1 = wreg[li][(q - 1) * 3 + 1];
                    float2 W2 = wreg[li][(q - 1) * 3 + 2];
                    float wa  = ch ? W0.y : W0.x;
                    float wbv = ch ? W1.y : W1.x;
                    float wc  = ch ? W2.y : W2.x;
                    acc10 += wa * t0.x + wbv * t0.y + wc * t0.z;
                    acc11 += wa * t0.y + wbv * t0.z + wc * t0.w;
                    acc12 += wa * t0.z + wbv * t0.w + wc * t1.x;
                    acc13 += wa * t0.w + wbv * t1.x + wc * t1.y;
                }
            }
        }
    }

    // butterfly reduce over l8 (lane bits 0-2)
    #pragma unroll
    for (int m = 1; m <= 4; m <<= 1) {
        acc00 += __shfl_xor(acc00, m); acc01 += __shfl_xor(acc01, m);
        acc02 += __shfl_xor(acc02, m); acc03 += __shfl_xor(acc03, m);
        acc10 += __shfl_xor(acc10, m); acc11 += __shfl_xor(acc11, m);
        acc12 += __shfl_xor(acc12, m); acc13 += __shfl_xor(acc13, m);
    }

    if (act && l8 == 0) {
        const int R0 = band * 4 + rp * 2;
        float* yp = y + (o * 28 + R0) * 28 + st * 4;
        *(float4*)yp        = make_float4(acc00, acc01, acc02, acc03);
        *(float4*)(yp + 28) = make_float4(acc10, acc11, acc12, acc13);
    }
}

extern "C" void kernel_launch(void* const* d_in, const int* in_sizes, int n_in,
                              void* d_out, int out_size, void* d_ws, size_t ws_size,
                              hipStream_t stream) {
    const float* x  = (const float*)d_in[0];   // (1,64,28,28) fp32
    const float* w1 = (const float*)d_in[1];   // (128,32,3,3,2) fp32
    const float* w2 = (const float*)d_in[2];   // (64,3,2) fp32
    float* yout = (float*)d_out;               // (1,128,28,28) fp32

    fused_kernel<<<dim3(448), dim3(256), 0, stream>>>(x, w1, w2, yout);
}